// Round 3
// baseline (302.168 us; speedup 1.0000x reference)
//
#include <hip/hip_runtime.h>
#include <hip/hip_bf16.h>

// x [4,2048,1024] fp32; Wq/Wk/Wv [1024,1024] fp32. Causal attention.
#define NB 4
#define SB 2048
#define DD 1024
#define BM 128
#define BN 128
#define BK 32

typedef __attribute__((ext_vector_type(8))) short bf16x8;
typedef __attribute__((ext_vector_type(4))) float f32x4;
typedef unsigned int u32;

__device__ __forceinline__ float bf2f(unsigned short u) {
    return __uint_as_float(((u32)u) << 16);
}
__device__ __forceinline__ short f2bf(float f) {
    u32 u = __float_as_uint(f);
    u32 r = (u + 0x7fffu + ((u >> 16) & 1u)) >> 16;
    return (short)r;
}

// ---------------------------------------------------------------------------
// Fused prep: blocks [0,4096) cast x fp32->bf16 (8 elem/thr);
// blocks [4096, 4096+768) cast+transpose Wq/Wk/Wv -> Wt[z][n][k] bf16.
// ---------------------------------------------------------------------------
__global__ __launch_bounds__(256) void prep(
    const float* __restrict__ x, const float* __restrict__ Wq,
    const float* __restrict__ Wk, const float* __restrict__ Wv,
    short* __restrict__ xb, short* __restrict__ Wt)
{
    __shared__ short t[64][65];
    const int bx = blockIdx.x;
    const int tid = threadIdx.x;
    if (bx < 4096) {
        const size_t i = ((size_t)bx * 256 + tid) * 8;
        float4 a = *(const float4*)&x[i];
        float4 b = *(const float4*)&x[i + 4];
        bf16x8 o;
        o[0] = f2bf(a.x); o[1] = f2bf(a.y); o[2] = f2bf(a.z); o[3] = f2bf(a.w);
        o[4] = f2bf(b.x); o[5] = f2bf(b.y); o[6] = f2bf(b.z); o[7] = f2bf(b.w);
        *(bf16x8*)&xb[i] = o;
        return;
    }
    const int idx = bx - 4096;
    const int z = idx >> 8;
    const int rr = idx & 255;
    const int k0 = (rr & 15) * 64;
    const int n0 = (rr >> 4) * 64;
    const float* W = (z == 0) ? Wq : (z == 1) ? Wk : Wv;
    short* T = Wt + (size_t)z * DD * DD;
    {
        const int r = tid >> 4;
        const int c = (tid & 15) * 4;
#pragma unroll
        for (int i = 0; i < 4; i++) {
            float4 v = *(const float4*)&W[(size_t)(k0 + i * 16 + r) * DD + n0 + c];
            t[i * 16 + r][c + 0] = f2bf(v.x);
            t[i * 16 + r][c + 1] = f2bf(v.y);
            t[i * 16 + r][c + 2] = f2bf(v.z);
            t[i * 16 + r][c + 3] = f2bf(v.w);
        }
    }
    __syncthreads();
    {
        const int r = tid >> 3;
        const int c = (tid & 7) * 8;
#pragma unroll
        for (int i = 0; i < 2; i++) {
            bf16x8 o;
#pragma unroll
            for (int j = 0; j < 8; j++) o[j] = t[c + j][i * 32 + r];
            *(bf16x8*)&T[(size_t)(n0 + i * 32 + r) * DD + k0 + c] = o;
        }
    }
}

// ---------------------------------------------------------------------------
// transpose V bf16: Vt[b][d][s] = V[b][s][d]. 64x64 LDS tile.
// ---------------------------------------------------------------------------
__global__ __launch_bounds__(256) void transpose_v(const short* __restrict__ V,
                                                   short* __restrict__ Vt)
{
    __shared__ short t[64][65];
    const int b = blockIdx.z;
    const int s0 = blockIdx.x * 64;
    const int d0 = blockIdx.y * 64;
    const short* Vb = V + (size_t)b * SB * DD;
    short* Tb = Vt + (size_t)b * DD * SB;
    const int tid = threadIdx.x;
    const int r = tid >> 3;
    const int c = (tid & 7) * 8;
#pragma unroll
    for (int i = 0; i < 2; i++) {
        bf16x8 v = *(const bf16x8*)&Vb[(size_t)(s0 + i * 32 + r) * DD + d0 + c];
#pragma unroll
        for (int j = 0; j < 8; j++) t[i * 32 + r][c + j] = v[j];
    }
    __syncthreads();
#pragma unroll
    for (int i = 0; i < 2; i++) {
        bf16x8 o;
#pragma unroll
        for (int j = 0; j < 8; j++) o[j] = t[c + j][i * 32 + r];
        *(bf16x8*)&Tb[(size_t)(d0 + i * 32 + r) * SB + s0 + c] = o;
    }
}

// ---------------------------------------------------------------------------
// Shared MFMA GEMM machinery: C[128x128] = A[128xK] * Bt[128xK]^T
// m97 structure: BK=32, 256 thr (4 waves, 2x2 of 64x64), global_load_lds x16B.
// ---------------------------------------------------------------------------
__device__ __forceinline__ void stage128x32(const short* __restrict__ g, int ld,
                                            short* lds, int tid) {
    const int wave = tid >> 6, lane = tid & 63;
    const int r = lane >> 2;
    const int c = (lane & 3) * 8;
#pragma unroll
    for (int i = 0; i < 2; i++) {
        const int chunk = wave * 2 + i;
        const short* gp = g + (size_t)(chunk * 16 + r) * ld + c;
        __builtin_amdgcn_global_load_lds(
            (const __attribute__((address_space(1))) u32*)gp,
            (__attribute__((address_space(3))) u32*)(lds + chunk * 512 + lane * 8),
            16, 0, 0);
    }
}

__device__ __forceinline__ void gemm_bt_body(
    const short* __restrict__ A, int lda, const short* __restrict__ Bt, int ldb,
    int m0, int n0, int kend, short* As, short* Bs, f32x4 (&acc)[4][4], int tid)
{
    const int lane = tid & 63;
    const int wave = tid >> 6;
    const int wm = (wave >> 1) * 64, wn = (wave & 1) * 64;
    const int fr = lane & 15;
    const int quad = lane >> 4;
    for (int k0 = 0; k0 < kend; k0 += BK) {
        stage128x32(A + (size_t)m0 * lda + k0, lda, As, tid);
        stage128x32(Bt + (size_t)n0 * ldb + k0, ldb, Bs, tid);
        __syncthreads();
        bf16x8 af[4], bf[4];
#pragma unroll
        for (int t = 0; t < 4; t++) {
            af[t] = *(const bf16x8*)&As[(wm + t * 16 + fr) * BK + quad * 8];
            bf[t] = *(const bf16x8*)&Bs[(wn + t * 16 + fr) * BK + quad * 8];
        }
#pragma unroll
        for (int mt = 0; mt < 4; mt++)
#pragma unroll
            for (int nt = 0; nt < 4; nt++)
                acc[mt][nt] = __builtin_amdgcn_mfma_f32_16x16x32_bf16(
                    af[mt], bf[nt], acc[mt][nt], 0, 0, 0);
        __syncthreads();
    }
}

// ---------------------------------------------------------------------------
// QKV projection: C = xb @ W (via Wt = W^T), output bf16 Q/K/V.
// ---------------------------------------------------------------------------
__global__ __launch_bounds__(256) void qkv_mfma(
    const short* __restrict__ xb, const short* __restrict__ Wt,
    short* __restrict__ Q, short* __restrict__ K, short* __restrict__ V)
{
    __shared__ short As[BM * BK], Bs[BN * BK];
    const int n0 = blockIdx.x * BN;
    const int m0 = blockIdx.y * BM;
    const int z = blockIdx.z;
    const short* B = Wt + (size_t)z * DD * DD;
    short* C = (z == 0) ? Q : (z == 1) ? K : V;
    f32x4 acc[4][4];
#pragma unroll
    for (int a = 0; a < 4; a++)
#pragma unroll
        for (int b = 0; b < 4; b++) acc[a][b] = (f32x4){0.f, 0.f, 0.f, 0.f};
    gemm_bt_body(xb, DD, B, DD, m0, n0, DD, As, Bs, acc, threadIdx.x);
    const int lane = threadIdx.x & 63, wave = threadIdx.x >> 6;
    const int wm = (wave >> 1) * 64, wn = (wave & 1) * 64;
    const int fr = lane & 15, quad = lane >> 4;
#pragma unroll
    for (int mt = 0; mt < 4; mt++)
#pragma unroll
        for (int nt = 0; nt < 4; nt++)
#pragma unroll
            for (int r = 0; r < 4; r++) {
                const size_t m = m0 + wm + mt * 16 + quad * 4 + r;
                const size_t n = n0 + wn + nt * 16 + fr;
                C[m * DD + n] = f2bf(acc[mt][nt][r]);
            }
}

// ---------------------------------------------------------------------------
// Scores: compact triangular grid — blockIdx.x in [0,136) decodes to
// (qt, kt) with kt <= qt. Sc[b][q][k] = scale * Q . K, fp32.
// ---------------------------------------------------------------------------
__global__ __launch_bounds__(256) void scores_mfma(
    const short* __restrict__ Q, const short* __restrict__ Kc,
    float* __restrict__ Sc)
{
    const int idx = blockIdx.x;
    int qt = (int)((__fsqrt_rn(8.f * idx + 1.f) - 1.f) * 0.5f);
    while ((qt + 1) * (qt + 2) / 2 <= idx) qt++;
    while (qt * (qt + 1) / 2 > idx) qt--;
    const int kt = idx - qt * (qt + 1) / 2;
    const int qm0 = qt * BM;
    const int kn0 = kt * BN;
    const int b = blockIdx.y;
    __shared__ short As[BM * BK], Bs[BN * BK];
    const short* Qb = Q + (size_t)b * SB * DD;
    const short* Kb = Kc + (size_t)b * SB * DD;
    float* Sb = Sc + (size_t)b * SB * SB;
    f32x4 acc[4][4];
#pragma unroll
    for (int a = 0; a < 4; a++)
#pragma unroll
        for (int c = 0; c < 4; c++) acc[a][c] = (f32x4){0.f, 0.f, 0.f, 0.f};
    gemm_bt_body(Qb, DD, Kb, DD, qm0, kn0, DD, As, Bs, acc, threadIdx.x);
    const int lane = threadIdx.x & 63, wave = threadIdx.x >> 6;
    const int wm = (wave >> 1) * 64, wn = (wave & 1) * 64;
    const int fr = lane & 15, quad = lane >> 4;
    const float scale = 0.03125f;  // 1/sqrt(1024)
#pragma unroll
    for (int mt = 0; mt < 4; mt++)
#pragma unroll
        for (int nt = 0; nt < 4; nt++)
#pragma unroll
            for (int r = 0; r < 4; r++) {
                const size_t q = qm0 + wm + mt * 16 + quad * 4 + r;
                const size_t k = kn0 + wn + nt * 16 + fr;
                Sb[q * SB + k] = acc[mt][nt][r] * scale;
            }
}

// ---------------------------------------------------------------------------
// Causal softmax. Row i only touches j < jlim = (i/128+1)*128 — pv never
// reads beyond the diagonal tile. Writes bf16 P into the first half of the
// fp32 row (stride 2*SB shorts). All reads precede all writes block-wide.
// ---------------------------------------------------------------------------
__global__ __launch_bounds__(256) void softmax_kernel(float* __restrict__ Sc)
{
    const int row = blockIdx.x;
    const int i = row & (SB - 1);
    const int jlim = ((i >> 7) + 1) << 7;  // wave-aligned (128 | 64)
    float* r = Sc + (size_t)row * SB;
    short* p = (short*)r;
    const int t = threadIdx.x;
    const int lane = t & 63, wave = t >> 6;
    __shared__ float red[8];

    float v[8];
    float mx = -1e30f;
#pragma unroll
    for (int c = 0; c < 8; c++) {
        const int j = c * 256 + t;
        const float s = (j <= i) ? r[j] : -1e30f;  // j>i lanes skip the load
        v[c] = s;
        mx = fmaxf(mx, s);
    }
#pragma unroll
    for (int o = 32; o > 0; o >>= 1) mx = fmaxf(mx, __shfl_down(mx, o));
    if (lane == 0) red[wave] = mx;
    __syncthreads();
    mx = fmaxf(fmaxf(red[0], red[1]), fmaxf(red[2], red[3]));

    float sum = 0.f;
#pragma unroll
    for (int c = 0; c < 8; c++) {
        const int j = c * 256 + t;
        const float e = (j <= i) ? __expf(v[c] - mx) : 0.f;
        v[c] = e;
        sum += e;
    }
#pragma unroll
    for (int o = 32; o > 0; o >>= 1) sum += __shfl_down(sum, o);
    if (lane == 0) red[4 + wave] = sum;
    __syncthreads();
    const float inv = 1.0f / (red[4] + red[5] + red[6] + red[7]);
#pragma unroll
    for (int c = 0; c < 8; c++) {
        const int j = c * 256 + t;
        if (j < jlim) p[j] = f2bf(v[c] * inv);
    }
}

// ---------------------------------------------------------------------------
// PV split-k: blockIdx.y in [0,40) -> (q-tile, k-chunk of <=512). Uniform
// <=16 k-iters per block; partials accumulated with native fp32 atomics
// into zero-initialized out. P row stride 2*SB shorts.
// ---------------------------------------------------------------------------
__global__ __launch_bounds__(256) void pv_mfma(
    const short* __restrict__ P, const short* __restrict__ Vt,
    float* __restrict__ O)
{
    static const int TQ[40] = {0, 1, 2, 3, 4, 4, 5, 5, 6, 6, 7, 7,
                               8, 8, 8, 9, 9, 9, 10, 10, 10, 11, 11, 11,
                               12, 12, 12, 12, 13, 13, 13, 13,
                               14, 14, 14, 14, 15, 15, 15, 15};
    static const int TC[40] = {0, 0, 0, 0, 0, 1, 0, 1, 0, 1, 0, 1,
                               0, 1, 2, 0, 1, 2, 0, 1, 2, 0, 1, 2,
                               0, 1, 2, 3, 0, 1, 2, 3,
                               0, 1, 2, 3, 0, 1, 2, 3};
    __shared__ short As[BM * BK], Bs[BN * BK];
    const int n0 = blockIdx.x * BN;
    const int qt = TQ[blockIdx.y], ch = TC[blockIdx.y];
    const int qm0 = qt * BM;
    const int kstart = ch * 512;
    const int kstop = min((qt + 1) * BM, kstart + 512);
    const int b = blockIdx.z;
    const short* Pb = P + (size_t)b * SB * (2 * SB) + kstart;
    const short* Vb = Vt + (size_t)b * DD * SB + kstart;
    float* Ob = O + (size_t)b * SB * DD;
    f32x4 acc[4][4];
#pragma unroll
    for (int a = 0; a < 4; a++)
#pragma unroll
        for (int c = 0; c < 4; c++) acc[a][c] = (f32x4){0.f, 0.f, 0.f, 0.f};
    gemm_bt_body(Pb, 2 * SB, Vb, SB, qm0, n0, kstop - kstart, As, Bs, acc,
                 threadIdx.x);
    const int lane = threadIdx.x & 63, wave = threadIdx.x >> 6;
    const int wm = (wave >> 1) * 64, wn = (wave & 1) * 64;
    const int fr = lane & 15, quad = lane >> 4;
#pragma unroll
    for (int mt = 0; mt < 4; mt++)
#pragma unroll
        for (int nt = 0; nt < 4; nt++)
#pragma unroll
            for (int r = 0; r < 4; r++) {
                const size_t q = qm0 + wm + mt * 16 + quad * 4 + r;
                const size_t n = n0 + wn + nt * 16 + fr;
                unsafeAtomicAdd(&Ob[q * DD + n], acc[mt][nt][r]);
            }
}

extern "C" void kernel_launch(void* const* d_in, const int* in_sizes, int n_in,
                              void* d_out, int out_size, void* d_ws, size_t ws_size,
                              hipStream_t stream)
{
    const float* x  = (const float*)d_in[0];
    const float* Wq = (const float*)d_in[1];
    const float* Wk = (const float*)d_in[2];
    const float* Wv = (const float*)d_in[3];
    float* out = (float*)d_out;

    // ws layout (117.44 MB): [Q][K][Vt] bf16, then region R hosting
    // {V, xb, Wt} during prep/qkv, re-used as Sc fp32 (+ in-place bf16 P)
    // from scores onward.
    const size_t QKV_ELEMS = (size_t)NB * SB * DD;
    short* Q  = (short*)d_ws;
    short* K  = Q + QKV_ELEMS;
    short* Vt = K + QKV_ELEMS;
    char*  R  = (char*)(Vt + QKV_ELEMS);
    short* V  = (short*)R;
    short* xb = V + QKV_ELEMS;
    short* Wt = xb + QKV_ELEMS;
    float* Sc = (float*)R;
    short* P  = (short*)R;

    hipMemsetAsync(out, 0, QKV_ELEMS * sizeof(float), stream);
    prep<<<dim3(4096 + 768), 256, 0, stream>>>(x, Wq, Wk, Wv, xb, Wt);
    qkv_mfma<<<dim3(DD / BN, (NB * SB) / BM, 3), 256, 0, stream>>>(xb, Wt, Q, K, V);
    transpose_v<<<dim3(SB / 64, DD / 64, NB), 256, 0, stream>>>(V, Vt);
    scores_mfma<<<dim3(136, NB), 256, 0, stream>>>(Q, K, Sc);
    softmax_kernel<<<dim3(NB * SB), 256, 0, stream>>>(Sc);
    pv_mfma<<<dim3(DD / BN, 40, NB), 256, 0, stream>>>(P, Vt, out);
}

// Round 4
// 270.691 us; speedup vs baseline: 1.1163x; 1.1163x over previous
//
#include <hip/hip_runtime.h>
#include <hip/hip_bf16.h>

// x [4,2048,1024] fp32; Wq/Wk/Wv [1024,1024] fp32. Causal attention.
#define NB 4
#define SB 2048
#define DD 1024
#define BM 128
#define BN 128
#define BK 32

typedef __attribute__((ext_vector_type(8))) short bf16x8;
typedef __attribute__((ext_vector_type(4))) float f32x4;
typedef unsigned int u32;

__device__ __forceinline__ float bf2f(unsigned short u) {
    return __uint_as_float(((u32)u) << 16);
}
__device__ __forceinline__ short f2bf(float f) {
    u32 u = __float_as_uint(f);
    u32 r = (u + 0x7fffu + ((u >> 16) & 1u)) >> 16;
    return (short)r;
}

// ---------------------------------------------------------------------------
// Fused prep: blocks [0,4096) cast x fp32->bf16 (8 elem/thr);
// blocks [4096, 4096+768) cast+transpose Wq/Wk/Wv -> Wt[z][n][k] bf16.
// ---------------------------------------------------------------------------
__global__ __launch_bounds__(256) void prep(
    const float* __restrict__ x, const float* __restrict__ Wq,
    const float* __restrict__ Wk, const float* __restrict__ Wv,
    short* __restrict__ xb, short* __restrict__ Wt)
{
    __shared__ short t[64][65];
    const int bx = blockIdx.x;
    const int tid = threadIdx.x;
    if (bx < 4096) {
        const size_t i = ((size_t)bx * 256 + tid) * 8;
        float4 a = *(const float4*)&x[i];
        float4 b = *(const float4*)&x[i + 4];
        bf16x8 o;
        o[0] = f2bf(a.x); o[1] = f2bf(a.y); o[2] = f2bf(a.z); o[3] = f2bf(a.w);
        o[4] = f2bf(b.x); o[5] = f2bf(b.y); o[6] = f2bf(b.z); o[7] = f2bf(b.w);
        *(bf16x8*)&xb[i] = o;
        return;
    }
    const int idx = bx - 4096;
    const int z = idx >> 8;
    const int rr = idx & 255;
    const int k0 = (rr & 15) * 64;
    const int n0 = (rr >> 4) * 64;
    const float* W = (z == 0) ? Wq : (z == 1) ? Wk : Wv;
    short* T = Wt + (size_t)z * DD * DD;
    {
        const int r = tid >> 4;
        const int c = (tid & 15) * 4;
#pragma unroll
        for (int i = 0; i < 4; i++) {
            float4 v = *(const float4*)&W[(size_t)(k0 + i * 16 + r) * DD + n0 + c];
            t[i * 16 + r][c + 0] = f2bf(v.x);
            t[i * 16 + r][c + 1] = f2bf(v.y);
            t[i * 16 + r][c + 2] = f2bf(v.z);
            t[i * 16 + r][c + 3] = f2bf(v.w);
        }
    }
    __syncthreads();
    {
        const int r = tid >> 3;
        const int c = (tid & 7) * 8;
#pragma unroll
        for (int i = 0; i < 2; i++) {
            bf16x8 o;
#pragma unroll
            for (int j = 0; j < 8; j++) o[j] = t[c + j][i * 32 + r];
            *(bf16x8*)&T[(size_t)(n0 + i * 32 + r) * DD + k0 + c] = o;
        }
    }
}

// ---------------------------------------------------------------------------
// transpose V bf16: Vt[b][d][s] = V[b][s][d]. 64x64 LDS tile.
// ---------------------------------------------------------------------------
__global__ __launch_bounds__(256) void transpose_v(const short* __restrict__ V,
                                                   short* __restrict__ Vt)
{
    __shared__ short t[64][65];
    const int b = blockIdx.z;
    const int s0 = blockIdx.x * 64;
    const int d0 = blockIdx.y * 64;
    const short* Vb = V + (size_t)b * SB * DD;
    short* Tb = Vt + (size_t)b * DD * SB;
    const int tid = threadIdx.x;
    const int r = tid >> 3;
    const int c = (tid & 7) * 8;
#pragma unroll
    for (int i = 0; i < 2; i++) {
        bf16x8 v = *(const bf16x8*)&Vb[(size_t)(s0 + i * 32 + r) * DD + d0 + c];
#pragma unroll
        for (int j = 0; j < 8; j++) t[i * 32 + r][c + j] = v[j];
    }
    __syncthreads();
#pragma unroll
    for (int i = 0; i < 2; i++) {
        bf16x8 o;
#pragma unroll
        for (int j = 0; j < 8; j++) o[j] = t[c + j][i * 32 + r];
        *(bf16x8*)&Tb[(size_t)(d0 + i * 32 + r) * SB + s0 + c] = o;
    }
}

// ---------------------------------------------------------------------------
// Shared MFMA GEMM machinery: C[128x128] = A[128xK] * Bt[128xK]^T
// m97 structure: BK=32, 256 thr (4 waves, 2x2 of 64x64), global_load_lds x16B.
// ---------------------------------------------------------------------------
__device__ __forceinline__ void stage128x32(const short* __restrict__ g, int ld,
                                            short* lds, int tid) {
    const int wave = tid >> 6, lane = tid & 63;
    const int r = lane >> 2;
    const int c = (lane & 3) * 8;
#pragma unroll
    for (int i = 0; i < 2; i++) {
        const int chunk = wave * 2 + i;
        const short* gp = g + (size_t)(chunk * 16 + r) * ld + c;
        __builtin_amdgcn_global_load_lds(
            (const __attribute__((address_space(1))) u32*)gp,
            (__attribute__((address_space(3))) u32*)(lds + chunk * 512 + lane * 8),
            16, 0, 0);
    }
}

__device__ __forceinline__ void gemm_bt_body(
    const short* __restrict__ A, int lda, const short* __restrict__ Bt, int ldb,
    int m0, int n0, int kend, short* As, short* Bs, f32x4 (&acc)[4][4], int tid)
{
    const int lane = tid & 63;
    const int wave = tid >> 6;
    const int wm = (wave >> 1) * 64, wn = (wave & 1) * 64;
    const int fr = lane & 15;
    const int quad = lane >> 4;
    for (int k0 = 0; k0 < kend; k0 += BK) {
        stage128x32(A + (size_t)m0 * lda + k0, lda, As, tid);
        stage128x32(Bt + (size_t)n0 * ldb + k0, ldb, Bs, tid);
        __syncthreads();
        bf16x8 af[4], bf[4];
#pragma unroll
        for (int t = 0; t < 4; t++) {
            af[t] = *(const bf16x8*)&As[(wm + t * 16 + fr) * BK + quad * 8];
            bf[t] = *(const bf16x8*)&Bs[(wn + t * 16 + fr) * BK + quad * 8];
        }
#pragma unroll
        for (int mt = 0; mt < 4; mt++)
#pragma unroll
            for (int nt = 0; nt < 4; nt++)
                acc[mt][nt] = __builtin_amdgcn_mfma_f32_16x16x32_bf16(
                    af[mt], bf[nt], acc[mt][nt], 0, 0, 0);
        __syncthreads();
    }
}

// ---------------------------------------------------------------------------
// QKV projection: C = xb @ W (via Wt = W^T), output bf16 Q/K/V.
// ---------------------------------------------------------------------------
__global__ __launch_bounds__(256) void qkv_mfma(
    const short* __restrict__ xb, const short* __restrict__ Wt,
    short* __restrict__ Q, short* __restrict__ K, short* __restrict__ V)
{
    __shared__ short As[BM * BK], Bs[BN * BK];
    const int n0 = blockIdx.x * BN;
    const int m0 = blockIdx.y * BM;
    const int z = blockIdx.z;
    const short* B = Wt + (size_t)z * DD * DD;
    short* C = (z == 0) ? Q : (z == 1) ? K : V;
    f32x4 acc[4][4];
#pragma unroll
    for (int a = 0; a < 4; a++)
#pragma unroll
        for (int b = 0; b < 4; b++) acc[a][b] = (f32x4){0.f, 0.f, 0.f, 0.f};
    gemm_bt_body(xb, DD, B, DD, m0, n0, DD, As, Bs, acc, threadIdx.x);
    const int lane = threadIdx.x & 63, wave = threadIdx.x >> 6;
    const int wm = (wave >> 1) * 64, wn = (wave & 1) * 64;
    const int fr = lane & 15, quad = lane >> 4;
#pragma unroll
    for (int mt = 0; mt < 4; mt++)
#pragma unroll
        for (int nt = 0; nt < 4; nt++)
#pragma unroll
            for (int r = 0; r < 4; r++) {
                const size_t m = m0 + wm + mt * 16 + quad * 4 + r;
                const size_t n = n0 + wn + nt * 16 + fr;
                C[m * DD + n] = f2bf(acc[mt][nt][r]);
            }
}

// ---------------------------------------------------------------------------
// Scores: compact triangular grid — blockIdx.x in [0,136) decodes to
// (qt, kt) with kt <= qt. Sc[b][q][k] = scale * Q . K, **bf16** out.
// ---------------------------------------------------------------------------
__global__ __launch_bounds__(256) void scores_mfma(
    const short* __restrict__ Q, const short* __restrict__ Kc,
    short* __restrict__ Sc)
{
    const int idx = blockIdx.x;
    int qt = (int)((__fsqrt_rn(8.f * idx + 1.f) - 1.f) * 0.5f);
    while ((qt + 1) * (qt + 2) / 2 <= idx) qt++;
    while (qt * (qt + 1) / 2 > idx) qt--;
    const int kt = idx - qt * (qt + 1) / 2;
    const int qm0 = qt * BM;
    const int kn0 = kt * BN;
    const int b = blockIdx.y;
    __shared__ short As[BM * BK], Bs[BN * BK];
    const short* Qb = Q + (size_t)b * SB * DD;
    const short* Kb = Kc + (size_t)b * SB * DD;
    short* Sb = Sc + (size_t)b * SB * SB;
    f32x4 acc[4][4];
#pragma unroll
    for (int a = 0; a < 4; a++)
#pragma unroll
        for (int c = 0; c < 4; c++) acc[a][c] = (f32x4){0.f, 0.f, 0.f, 0.f};
    gemm_bt_body(Qb, DD, Kb, DD, qm0, kn0, DD, As, Bs, acc, threadIdx.x);
    const int lane = threadIdx.x & 63, wave = threadIdx.x >> 6;
    const int wm = (wave >> 1) * 64, wn = (wave & 1) * 64;
    const int fr = lane & 15, quad = lane >> 4;
    const float scale = 0.03125f;  // 1/sqrt(1024)
#pragma unroll
    for (int mt = 0; mt < 4; mt++)
#pragma unroll
        for (int nt = 0; nt < 4; nt++)
#pragma unroll
            for (int r = 0; r < 4; r++) {
                const size_t q = qm0 + wm + mt * 16 + quad * 4 + r;
                const size_t k = kn0 + wn + nt * 16 + fr;
                Sb[q * SB + k] = f2bf(acc[mt][nt][r] * scale);
            }
}

// ---------------------------------------------------------------------------
// Causal softmax on bf16 scores, in place (row stride SB shorts). Row i only
// touches j < jlim = (i/128+1)*128 — pv reads exactly k < (qt+1)*128.
// Block-local: all reads precede all writes.
// ---------------------------------------------------------------------------
__global__ __launch_bounds__(256) void softmax_kernel(short* __restrict__ Sc)
{
    const int row = blockIdx.x;
    const int i = row & (SB - 1);
    const int jlim = ((i >> 7) + 1) << 7;
    short* r = Sc + (size_t)row * SB;
    const int t = threadIdx.x;
    const int lane = t & 63, wave = t >> 6;
    __shared__ float red[8];

    float v[8];
    float mx = -1e30f;
#pragma unroll
    for (int c = 0; c < 8; c++) {
        const int j = c * 256 + t;
        const float s = (j <= i) ? bf2f((unsigned short)r[j]) : -1e30f;
        v[c] = s;
        mx = fmaxf(mx, s);
    }
#pragma unroll
    for (int o = 32; o > 0; o >>= 1) mx = fmaxf(mx, __shfl_down(mx, o));
    if (lane == 0) red[wave] = mx;
    __syncthreads();
    mx = fmaxf(fmaxf(red[0], red[1]), fmaxf(red[2], red[3]));

    float sum = 0.f;
#pragma unroll
    for (int c = 0; c < 8; c++) {
        const int j = c * 256 + t;
        const float e = (j <= i) ? __expf(v[c] - mx) : 0.f;
        v[c] = e;
        sum += e;
    }
#pragma unroll
    for (int o = 32; o > 0; o >>= 1) sum += __shfl_down(sum, o);
    if (lane == 0) red[4 + wave] = sum;
    __syncthreads();
    const float inv = 1.0f / (red[4] + red[5] + red[6] + red[7]);
#pragma unroll
    for (int c = 0; c < 8; c++) {
        const int j = c * 256 + t;
        if (j < jlim) r[j] = f2bf(v[c] * inv);
    }
}

// ---------------------------------------------------------------------------
// PV split-k, atomic-free. blockIdx.y in [0,24):
//   y<16:  qt=y, k in [0, min(1024,(qt+1)*128))  -> store DIRECT to out
//          (every out element covered exactly once; no memset needed)
//   y>=16: qt=y-8, k in [1024, (qt+1)*128)       -> store to partial Pp
// All blocks <= 32 k-iters. reduce_pv adds Pp into out's upper half.
// ---------------------------------------------------------------------------
__global__ __launch_bounds__(256) void pv_mfma(
    const short* __restrict__ P, const short* __restrict__ Vt,
    float* __restrict__ O, float* __restrict__ Pp)
{
    __shared__ short As[BM * BK], Bs[BN * BK];
    const int n0 = blockIdx.x * BN;
    const int y = blockIdx.y;
    const int chunk1 = (y >= 16);
    const int qt = chunk1 ? (y - 8) : y;
    const int qm0 = qt * BM;
    const int kstart = chunk1 ? 1024 : 0;
    const int kstop = chunk1 ? (qt + 1) * BM : min(1024, (qt + 1) * BM);
    const int b = blockIdx.z;
    const short* Pb = P + (size_t)b * SB * SB + kstart;
    const short* Vb = Vt + (size_t)b * DD * SB + kstart;
    f32x4 acc[4][4];
#pragma unroll
    for (int a = 0; a < 4; a++)
#pragma unroll
        for (int c = 0; c < 4; c++) acc[a][c] = (f32x4){0.f, 0.f, 0.f, 0.f};
    gemm_bt_body(Pb, SB, Vb, SB, qm0, n0, kstop - kstart, As, Bs, acc,
                 threadIdx.x);
    const int lane = threadIdx.x & 63, wave = threadIdx.x >> 6;
    const int wm = (wave >> 1) * 64, wn = (wave & 1) * 64;
    const int fr = lane & 15, quad = lane >> 4;
    // chunk0 -> O[b][q][n]; chunk1 -> Pp[b][q-1024][n]
    float* dst = chunk1 ? (Pp + (size_t)b * 1024 * DD - (size_t)1024 * DD)
                        : (O + (size_t)b * SB * DD);
    if (chunk1) dst = Pp + (size_t)b * 1024 * DD;  // base for (q-1024) rows
    const int qoff = chunk1 ? 1024 : 0;
#pragma unroll
    for (int mt = 0; mt < 4; mt++)
#pragma unroll
        for (int nt = 0; nt < 4; nt++)
#pragma unroll
            for (int r = 0; r < 4; r++) {
                const size_t q = qm0 + wm + mt * 16 + quad * 4 + r - qoff;
                const size_t n = n0 + wn + nt * 16 + fr;
                dst[q * DD + n] = acc[mt][nt][r];
            }
}

// ---------------------------------------------------------------------------
// reduce: O[b][1024+q'][:] += Pp[b][q'][:], 4 floats/thread.
// ---------------------------------------------------------------------------
__global__ __launch_bounds__(256) void reduce_pv(const float* __restrict__ Pp,
                                                 float* __restrict__ O)
{
    const size_t e = ((size_t)blockIdx.x * 256 + threadIdx.x) * 4;
    const size_t b = e / ((size_t)1024 * DD);
    const size_t rem = e - b * (size_t)1024 * DD;
    float4 p = *(const float4*)&Pp[e];
    float* o = &O[b * (size_t)SB * DD + (size_t)1024 * DD + rem];
    float4 v = *(const float4*)o;
    v.x += p.x; v.y += p.y; v.z += p.z; v.w += p.w;
    *(float4*)o = v;
}

extern "C" void kernel_launch(void* const* d_in, const int* in_sizes, int n_in,
                              void* d_out, int out_size, void* d_ws, size_t ws_size,
                              hipStream_t stream)
{
    const float* x  = (const float*)d_in[0];
    const float* Wq = (const float*)d_in[1];
    const float* Wk = (const float*)d_in[2];
    const float* Wv = (const float*)d_in[3];
    float* out = (float*)d_out;

    // ws layout (117.44 MB): [Q][K][Vt] bf16 (50.3 MB), then region R:
    //   during prep/qkv: {V, xb, Wt} (39.9 MB)
    //   from scores on:  Sc bf16 [B*S*S] (33.6 MB) + Pp fp32 [B*1024*DD]
    //                    (16.8 MB) = 50.3 MB  (< 67.1 MB available)
    const size_t QKV_ELEMS = (size_t)NB * SB * DD;
    short* Q  = (short*)d_ws;
    short* K  = Q + QKV_ELEMS;
    short* Vt = K + QKV_ELEMS;
    char*  R  = (char*)(Vt + QKV_ELEMS);
    short* V  = (short*)R;
    short* xb = V + QKV_ELEMS;
    short* Wt = xb + QKV_ELEMS;
    short* Sc = (short*)R;
    float* Pp = (float*)(Sc + (size_t)NB * SB * SB);

    prep<<<dim3(4096 + 768), 256, 0, stream>>>(x, Wq, Wk, Wv, xb, Wt);
    qkv_mfma<<<dim3(DD / BN, (NB * SB) / BM, 3), 256, 0, stream>>>(xb, Wt, Q, K, V);
    transpose_v<<<dim3(SB / 64, DD / 64, NB), 256, 0, stream>>>(V, Vt);
    scores_mfma<<<dim3(136, NB), 256, 0, stream>>>(Q, K, Sc);
    softmax_kernel<<<dim3(NB * SB), 256, 0, stream>>>(Sc);
    pv_mfma<<<dim3(DD / BN, 24, NB), 256, 0, stream>>>(Sc, Vt, out, Pp);
    reduce_pv<<<dim3((unsigned)((size_t)NB * 1024 * DD / 4 / 256)), 256, 0,
                stream>>>(Pp, out);
}